// Round 1
// baseline (879.934 us; speedup 1.0000x reference)
//
#include <hip/hip_runtime.h>

// EtaGNN: 2x SAGE-conv (mean agg) + factorized MLP link predictor.
// Strategy: project-then-aggregate (linearity of mean), CSR gather (no f32 atomics),
// factorized query head (A[u]+B[v]+t*wt).

constexpr int NN = 50000;   // nodes
constexpr int NE = 800000;  // edges
constexpr int NQ = 400000;  // queries

// ---------------- CSR build ----------------
__global__ void count_kernel(const int* __restrict__ dst, int* __restrict__ cnt) {
    int e = blockIdx.x * 256 + threadIdx.x;
    if (e < NE) atomicAdd(&cnt[dst[e]], 1);
}

constexpr int SCHUNK = 1024;
constexpr int SBLK = (NN + SCHUNK - 1) / SCHUNK;  // 49 blocks, covers NN+1 indices (50176)

__global__ void scan_sum_kernel(const int* __restrict__ cnt, int* __restrict__ bsum) {
    __shared__ int sd[256];
    int t = threadIdx.x;
    int base = blockIdx.x * SCHUNK;
    int s = 0;
#pragma unroll
    for (int j = 0; j < 4; ++j) {
        int i = base + t + j * 256;
        if (i < NN) s += cnt[i];
    }
    sd[t] = s; __syncthreads();
    for (int off = 128; off > 0; off >>= 1) {
        if (t < off) sd[t] += sd[t + off];
        __syncthreads();
    }
    if (t == 0) bsum[blockIdx.x] = sd[0];
}

__global__ void scan_block_kernel(int* bsum) {  // 1 wave, exclusive scan in place
    int t = threadIdx.x;
    int orig = (t < SBLK) ? bsum[t] : 0;
    int v = orig;
#pragma unroll
    for (int off = 1; off < 64; off <<= 1) {
        int w = __shfl_up(v, off);
        if (t >= off) v += w;
    }
    if (t < SBLK) bsum[t] = v - orig;
}

__global__ void scan_write_kernel(const int* __restrict__ bsum, int* __restrict__ row_start,
                                  int* __restrict__ cursor /* in: counts, out: row_start copy */) {
    __shared__ int wsum[4];
    int t = threadIdx.x, lane = t & 63, wid = t >> 6;
    int base = blockIdx.x * SCHUNK;
    int v[4]; int s = 0;
#pragma unroll
    for (int j = 0; j < 4; ++j) {
        int i = base + t * 4 + j;
        v[j] = (i < NN) ? cursor[i] : 0;
        s += v[j];
    }
    int orig = s;
#pragma unroll
    for (int off = 1; off < 64; off <<= 1) {
        int w = __shfl_up(s, off);
        if (lane >= off) s += w;
    }
    if (lane == 63) wsum[wid] = s;
    __syncthreads();
    int woff = 0;
    for (int w = 0; w < wid; ++w) woff += wsum[w];
    int excl = bsum[blockIdx.x] + woff + (s - orig);
#pragma unroll
    for (int j = 0; j < 4; ++j) {
        int i = base + t * 4 + j;
        if (i <= NN) {
            row_start[i] = excl;
            if (i < NN) { cursor[i] = excl; excl += v[j]; }
        }
    }
}

__global__ void fill_kernel(const int* __restrict__ src, const int* __restrict__ dst,
                            int* __restrict__ cursor, int* __restrict__ csr_src) {
    int e = blockIdx.x * 256 + threadIdx.x;
    if (e < NE) {
        int p = atomicAdd(&cursor[dst[e]], 1);
        csr_src[p] = src[e];
    }
}

// ---------------- dual GEMM: outA = in @ Wa.T, outB = in @ Wb.T  (Cout=64) ----------------
// block = 256 threads, 32 rows/block, thread owns 1 col x 8 rows for both outputs.
template <int K>
__global__ __launch_bounds__(256) void dual_gemm_kernel(
    const float* __restrict__ in,
    const float* __restrict__ Wa, int wsA,
    const float* __restrict__ Wb, int wsB,
    float* __restrict__ outA, float* __restrict__ outB) {
    __shared__ float WaT[64][65];  // [k][c], padded: conflict-free r/w
    __shared__ float WbT[64][65];
    __shared__ float X[32][K];
    int t = threadIdx.x;
    int rbase = blockIdx.x * 32;
    for (int idx = t; idx < 32 * K; idx += 256) {
        int r = idx / K, k = idx % K;
        int gr = rbase + r;
        X[r][k] = (gr < NN) ? in[(size_t)gr * K + k] : 0.f;
    }
    int c = t & 63, g = t >> 6;
    float accA[8], accB[8];
#pragma unroll
    for (int j = 0; j < 8; ++j) { accA[j] = 0.f; accB[j] = 0.f; }
#pragma unroll
    for (int ph = 0; ph < K / 64; ++ph) {
        __syncthreads();  // X staged / previous phase consumed
        for (int idx = t; idx < 4096; idx += 256) {
            int cc = idx >> 6, kk = idx & 63;
            WaT[kk][cc] = Wa[cc * wsA + ph * 64 + kk];
            WbT[kk][cc] = Wb[cc * wsB + ph * 64 + kk];
        }
        __syncthreads();
        for (int k2 = 0; k2 < 64; k2 += 4) {
            float4 xv[8];
#pragma unroll
            for (int j = 0; j < 8; ++j)
                xv[j] = *reinterpret_cast<const float4*>(&X[g * 8 + j][ph * 64 + k2]);
#pragma unroll
            for (int kk = 0; kk < 4; ++kk) {
                float wa = WaT[k2 + kk][c];
                float wb = WbT[k2 + kk][c];
#pragma unroll
                for (int j = 0; j < 8; ++j) {
                    float xval = (&xv[j].x)[kk];
                    accA[j] = fmaf(xval, wa, accA[j]);
                    accB[j] = fmaf(xval, wb, accB[j]);
                }
            }
        }
    }
#pragma unroll
    for (int j = 0; j < 8; ++j) {
        int gr = rbase + g * 8 + j;
        if (gr < NN) {
            outA[(size_t)gr * 64 + c] = accA[j];
            outB[(size_t)gr * 64 + c] = accB[j];
        }
    }
}

// ---------------- aggregation: out = relu(sum(p[src])/max(deg,1) + bias + selfp) ----------------
// one wave per node, lane = feature
__global__ __launch_bounds__(256) void agg_kernel(
    const float* __restrict__ p, const float* __restrict__ selfp,
    const float* __restrict__ bias, const int* __restrict__ row_start,
    const int* __restrict__ csr_src, float* __restrict__ out) {
    int node = blockIdx.x * 4 + (threadIdx.x >> 6);
    int lane = threadIdx.x & 63;
    if (node >= NN) return;
    int s0 = row_start[node], s1 = row_start[node + 1];
    float acc = 0.f;
    for (int e = s0; e < s1; ++e) {
        int s = csr_src[e];
        acc += p[(size_t)s * 64 + lane];
    }
    float inv = 1.f / fmaxf((float)(s1 - s0), 1.f);
    float v = fmaf(acc, inv, bias[lane] + selfp[(size_t)node * 64 + lane]);
    out[(size_t)node * 64 + lane] = fmaxf(v, 0.f);
}

// ---------------- query head: out = relu(A[u]+B[v]+t*wt+bm1) . Wm2 + bm2 ----------------
__global__ __launch_bounds__(256) void query_kernel(
    const int* __restrict__ uv, const float* __restrict__ tf,
    const float* __restrict__ A, const float* __restrict__ B,
    const float* __restrict__ Wm1, const float* __restrict__ bm1,
    const float* __restrict__ Wm2, const float* __restrict__ bm2,
    float* __restrict__ out) {
    int q = blockIdx.x * 4 + (threadIdx.x >> 6);
    int lane = threadIdx.x & 63;
    if (q >= NQ) return;
    int u = uv[2 * q], v = uv[2 * q + 1];
    float t = tf[q];
    float z = A[(size_t)u * 64 + lane] + B[(size_t)v * 64 + lane]
            + t * Wm1[lane * 129 + 128] + bm1[lane];
    z = fmaxf(z, 0.f) * Wm2[lane];
#pragma unroll
    for (int off = 32; off > 0; off >>= 1) z += __shfl_down(z, off);
    if (lane == 0) out[q] = z + bm2[0];
}

extern "C" void kernel_launch(void* const* d_in, const int* in_sizes, int n_in,
                              void* d_out, int out_size, void* d_ws, size_t ws_size,
                              hipStream_t stream) {
    const float* x   = (const float*)d_in[0];
    const int*   ei  = (const int*)d_in[1];
    const int*   uv  = (const int*)d_in[2];
    const float* tf  = (const float*)d_in[3];
    const float* W1l = (const float*)d_in[4];
    const float* b1  = (const float*)d_in[5];
    const float* W1r = (const float*)d_in[6];
    const float* W2l = (const float*)d_in[7];
    const float* b2  = (const float*)d_in[8];
    const float* W2r = (const float*)d_in[9];
    const float* Wm1 = (const float*)d_in[10];
    const float* bm1 = (const float*)d_in[11];
    const float* Wm2 = (const float*)d_in[12];
    const float* bm2 = (const float*)d_in[13];
    float* out = (float*)d_out;

    char* ws = (char*)d_ws;
    size_t off = 0;
    auto take = [&](size_t bytes) -> void* {
        void* p = ws + off;
        off = (off + bytes + 255) & ~(size_t)255;
        return p;
    };
    int* row_start = (int*)take((NN + 1) * sizeof(int));
    int* cursor    = (int*)take((size_t)NN * sizeof(int));   // doubles as per-node count
    int* csr_src   = (int*)take((size_t)NE * sizeof(int));
    int* bsum      = (int*)take(64 * sizeof(int));
    float* buf0 = (float*)take((size_t)NN * 64 * sizeof(float));
    float* buf1 = (float*)take((size_t)NN * 64 * sizeof(float));
    float* buf2 = (float*)take((size_t)NN * 64 * sizeof(float));
    (void)in_sizes; (void)n_in; (void)out_size; (void)ws_size;

    const int* esrc = ei;
    const int* edst = ei + NE;

    // CSR build (counts -> exclusive scan -> fill)
    hipMemsetAsync(cursor, 0, NN * sizeof(int), stream);
    count_kernel<<<(NE + 255) / 256, 256, 0, stream>>>(edst, cursor);
    scan_sum_kernel<<<SBLK, 256, 0, stream>>>(cursor, bsum);
    scan_block_kernel<<<1, 64, 0, stream>>>(bsum);
    scan_write_kernel<<<SBLK, 256, 0, stream>>>(bsum, row_start, cursor);
    fill_kernel<<<(NE + 255) / 256, 256, 0, stream>>>(esrc, edst, cursor, csr_src);

    // Layer 1: p1 = x@W1l.T (buf0), xr = x@W1r.T (buf1); h1 = relu(mean+b1+xr) (buf2)
    dual_gemm_kernel<128><<<(NN + 31) / 32, 256, 0, stream>>>(x, W1l, 128, W1r, 128, buf0, buf1);
    agg_kernel<<<(NN + 3) / 4, 256, 0, stream>>>(buf0, buf1, b1, row_start, csr_src, buf2);
    // Layer 2
    dual_gemm_kernel<64><<<(NN + 31) / 32, 256, 0, stream>>>(buf2, W2l, 64, W2r, 64, buf0, buf1);
    agg_kernel<<<(NN + 3) / 4, 256, 0, stream>>>(buf0, buf1, b2, row_start, csr_src, buf2);
    // MLP factorization: A = h2@Wm1[:, :64].T (buf0), B = h2@Wm1[:, 64:128].T (buf1)
    dual_gemm_kernel<64><<<(NN + 31) / 32, 256, 0, stream>>>(buf2, Wm1, 129, Wm1 + 64, 129, buf0, buf1);
    // Per-query head
    query_kernel<<<(NQ + 3) / 4, 256, 0, stream>>>(uv, tf, buf0, buf1, Wm1, bm1, Wm2, bm2, out);
}

// Round 2
// 460.611 us; speedup vs baseline: 1.9104x; 1.9104x over previous
//
#include <hip/hip_runtime.h>

// EtaGNN: 2x SAGE-conv (mean agg) + factorized MLP link predictor.
// Strategy: project-then-aggregate (linearity of mean), CSR gather (no f32 atomics),
// factorized query head (A[u]+B[v]+t*wt).
// R1: dual_gemm rewritten register-light (was spilling at 256 VGPRs -> 360MB/dispatch
// scratch traffic). X read via wave-uniform global broadcast, only W tiles in LDS.

constexpr int NN = 50000;   // nodes
constexpr int NE = 800000;  // edges
constexpr int NQ = 400000;  // queries

// ---------------- CSR build ----------------
__global__ void count_kernel(const int* __restrict__ dst, int* __restrict__ cnt) {
    int e = blockIdx.x * 256 + threadIdx.x;
    if (e < NE) atomicAdd(&cnt[dst[e]], 1);
}

constexpr int SCHUNK = 1024;
constexpr int SBLK = (NN + SCHUNK - 1) / SCHUNK;  // 49 blocks

__global__ void scan_sum_kernel(const int* __restrict__ cnt, int* __restrict__ bsum) {
    __shared__ int sd[256];
    int t = threadIdx.x;
    int base = blockIdx.x * SCHUNK;
    int s = 0;
#pragma unroll
    for (int j = 0; j < 4; ++j) {
        int i = base + t + j * 256;
        if (i < NN) s += cnt[i];
    }
    sd[t] = s; __syncthreads();
    for (int off = 128; off > 0; off >>= 1) {
        if (t < off) sd[t] += sd[t + off];
        __syncthreads();
    }
    if (t == 0) bsum[blockIdx.x] = sd[0];
}

__global__ void scan_block_kernel(int* bsum) {  // 1 wave, exclusive scan in place
    int t = threadIdx.x;
    int orig = (t < SBLK) ? bsum[t] : 0;
    int v = orig;
#pragma unroll
    for (int off = 1; off < 64; off <<= 1) {
        int w = __shfl_up(v, off);
        if (t >= off) v += w;
    }
    if (t < SBLK) bsum[t] = v - orig;
}

__global__ void scan_write_kernel(const int* __restrict__ bsum, int* __restrict__ row_start,
                                  int* __restrict__ cursor /* in: counts, out: cursor */) {
    __shared__ int wsum[4];
    int t = threadIdx.x, lane = t & 63, wid = t >> 6;
    int base = blockIdx.x * SCHUNK;
    int v[4]; int s = 0;
#pragma unroll
    for (int j = 0; j < 4; ++j) {
        int i = base + t * 4 + j;
        v[j] = (i < NN) ? cursor[i] : 0;
        s += v[j];
    }
    int orig = s;
#pragma unroll
    for (int off = 1; off < 64; off <<= 1) {
        int w = __shfl_up(s, off);
        if (lane >= off) s += w;
    }
    if (lane == 63) wsum[wid] = s;
    __syncthreads();
    int woff = 0;
    for (int w = 0; w < wid; ++w) woff += wsum[w];
    int excl = bsum[blockIdx.x] + woff + (s - orig);
#pragma unroll
    for (int j = 0; j < 4; ++j) {
        int i = base + t * 4 + j;
        if (i <= NN) {
            row_start[i] = excl;
            if (i < NN) { cursor[i] = excl; excl += v[j]; }
        }
    }
}

__global__ void fill_kernel(const int* __restrict__ src, const int* __restrict__ dst,
                            int* __restrict__ cursor, int* __restrict__ csr_src) {
    int e = blockIdx.x * 256 + threadIdx.x;
    if (e < NE) {
        int p = atomicAdd(&cursor[dst[e]], 1);
        csr_src[p] = src[e];
    }
}

// ---------------- dual GEMM: outA = in @ Wa.T, outB = in @ Wb.T  (Cout=64) ----------------
// 256 threads = 4 waves; wave owns 8 rows, lane owns 1 col. X via wave-uniform
// global broadcast loads (one float4 live at a time); only W tiles in LDS.
template <int K>
__global__ __launch_bounds__(256, 4) void dual_gemm_kernel(
    const float* __restrict__ in,
    const float* __restrict__ Wa, int wsA,
    const float* __restrict__ Wb, int wsB,
    float* __restrict__ outA, float* __restrict__ outB) {
    __shared__ float WaT[64][65];  // [k][c], 2-way bank aliasing (free)
    __shared__ float WbT[64][65];
    int t = threadIdx.x;
    int c = t & 63, g = t >> 6;
    int rbase = blockIdx.x * 32 + g * 8;
    const float* xrow[8];
#pragma unroll
    for (int j = 0; j < 8; ++j) {
        int gr = rbase + j;
        xrow[j] = in + (size_t)(gr < NN ? gr : NN - 1) * K;  // clamp; store guarded below
    }
    float accA[8], accB[8];
#pragma unroll
    for (int j = 0; j < 8; ++j) { accA[j] = 0.f; accB[j] = 0.f; }
    for (int ph = 0; ph < K / 64; ++ph) {
        if (ph) __syncthreads();
        for (int idx = t; idx < 4096; idx += 256) {
            int cc = idx >> 6, kk = idx & 63;
            WaT[kk][cc] = Wa[cc * wsA + ph * 64 + kk];
            WbT[kk][cc] = Wb[cc * wsB + ph * 64 + kk];
        }
        __syncthreads();
        for (int k2 = 0; k2 < 64; k2 += 4) {
            float wa[4], wb[4];
#pragma unroll
            for (int kk = 0; kk < 4; ++kk) {
                wa[kk] = WaT[k2 + kk][c];
                wb[kk] = WbT[k2 + kk][c];
            }
#pragma unroll
            for (int j = 0; j < 8; ++j) {
                float4 xv = *reinterpret_cast<const float4*>(xrow[j] + ph * 64 + k2);
                accA[j] = fmaf(xv.x, wa[0], accA[j]);
                accB[j] = fmaf(xv.x, wb[0], accB[j]);
                accA[j] = fmaf(xv.y, wa[1], accA[j]);
                accB[j] = fmaf(xv.y, wb[1], accB[j]);
                accA[j] = fmaf(xv.z, wa[2], accA[j]);
                accB[j] = fmaf(xv.z, wb[2], accB[j]);
                accA[j] = fmaf(xv.w, wa[3], accA[j]);
                accB[j] = fmaf(xv.w, wb[3], accB[j]);
            }
        }
    }
#pragma unroll
    for (int j = 0; j < 8; ++j) {
        int gr = rbase + j;
        if (gr < NN) {
            outA[(size_t)gr * 64 + c] = accA[j];
            outB[(size_t)gr * 64 + c] = accB[j];
        }
    }
}

// ---------------- aggregation: out = relu(sum(p[src])/max(deg,1) + bias + selfp) ----------------
__global__ __launch_bounds__(256) void agg_kernel(
    const float* __restrict__ p, const float* __restrict__ selfp,
    const float* __restrict__ bias, const int* __restrict__ row_start,
    const int* __restrict__ csr_src, float* __restrict__ out) {
    int node = blockIdx.x * 4 + (threadIdx.x >> 6);
    int lane = threadIdx.x & 63;
    if (node >= NN) return;
    int s0 = row_start[node], s1 = row_start[node + 1];
    float acc = 0.f;
    for (int e = s0; e < s1; ++e) {
        int s = csr_src[e];
        acc += p[(size_t)s * 64 + lane];
    }
    float inv = 1.f / fmaxf((float)(s1 - s0), 1.f);
    float v = fmaf(acc, inv, bias[lane] + selfp[(size_t)node * 64 + lane]);
    out[(size_t)node * 64 + lane] = fmaxf(v, 0.f);
}

// ---------------- query head: out = relu(A[u]+B[v]+t*wt+bm1) . Wm2 + bm2 ----------------
__global__ __launch_bounds__(256) void query_kernel(
    const int* __restrict__ uv, const float* __restrict__ tf,
    const float* __restrict__ A, const float* __restrict__ B,
    const float* __restrict__ Wm1, const float* __restrict__ bm1,
    const float* __restrict__ Wm2, const float* __restrict__ bm2,
    float* __restrict__ out) {
    int q = blockIdx.x * 4 + (threadIdx.x >> 6);
    int lane = threadIdx.x & 63;
    if (q >= NQ) return;
    int u = uv[2 * q], v = uv[2 * q + 1];
    float t = tf[q];
    float z = A[(size_t)u * 64 + lane] + B[(size_t)v * 64 + lane]
            + t * Wm1[lane * 129 + 128] + bm1[lane];
    z = fmaxf(z, 0.f) * Wm2[lane];
#pragma unroll
    for (int off = 32; off > 0; off >>= 1) z += __shfl_down(z, off);
    if (lane == 0) out[q] = z + bm2[0];
}

extern "C" void kernel_launch(void* const* d_in, const int* in_sizes, int n_in,
                              void* d_out, int out_size, void* d_ws, size_t ws_size,
                              hipStream_t stream) {
    const float* x   = (const float*)d_in[0];
    const int*   ei  = (const int*)d_in[1];
    const int*   uv  = (const int*)d_in[2];
    const float* tf  = (const float*)d_in[3];
    const float* W1l = (const float*)d_in[4];
    const float* b1  = (const float*)d_in[5];
    const float* W1r = (const float*)d_in[6];
    const float* W2l = (const float*)d_in[7];
    const float* b2  = (const float*)d_in[8];
    const float* W2r = (const float*)d_in[9];
    const float* Wm1 = (const float*)d_in[10];
    const float* bm1 = (const float*)d_in[11];
    const float* Wm2 = (const float*)d_in[12];
    const float* bm2 = (const float*)d_in[13];
    float* out = (float*)d_out;

    char* ws = (char*)d_ws;
    size_t off = 0;
    auto take = [&](size_t bytes) -> void* {
        void* p = ws + off;
        off = (off + bytes + 255) & ~(size_t)255;
        return p;
    };
    int* row_start = (int*)take((NN + 1) * sizeof(int));
    int* cursor    = (int*)take((size_t)NN * sizeof(int));
    int* csr_src   = (int*)take((size_t)NE * sizeof(int));
    int* bsum      = (int*)take(64 * sizeof(int));
    float* buf0 = (float*)take((size_t)NN * 64 * sizeof(float));
    float* buf1 = (float*)take((size_t)NN * 64 * sizeof(float));
    float* buf2 = (float*)take((size_t)NN * 64 * sizeof(float));
    (void)in_sizes; (void)n_in; (void)out_size; (void)ws_size;

    const int* esrc = ei;
    const int* edst = ei + NE;

    // CSR build (counts -> exclusive scan -> fill)
    hipMemsetAsync(cursor, 0, NN * sizeof(int), stream);
    count_kernel<<<(NE + 255) / 256, 256, 0, stream>>>(edst, cursor);
    scan_sum_kernel<<<SBLK, 256, 0, stream>>>(cursor, bsum);
    scan_block_kernel<<<1, 64, 0, stream>>>(bsum);
    scan_write_kernel<<<SBLK, 256, 0, stream>>>(bsum, row_start, cursor);
    fill_kernel<<<(NE + 255) / 256, 256, 0, stream>>>(esrc, edst, cursor, csr_src);

    // Layer 1: p1 = x@W1l.T (buf0), xr = x@W1r.T (buf1); h1 = relu(mean+b1+xr) (buf2)
    dual_gemm_kernel<128><<<(NN + 31) / 32, 256, 0, stream>>>(x, W1l, 128, W1r, 128, buf0, buf1);
    agg_kernel<<<(NN + 3) / 4, 256, 0, stream>>>(buf0, buf1, b1, row_start, csr_src, buf2);
    // Layer 2
    dual_gemm_kernel<64><<<(NN + 31) / 32, 256, 0, stream>>>(buf2, W2l, 64, W2r, 64, buf0, buf1);
    agg_kernel<<<(NN + 3) / 4, 256, 0, stream>>>(buf0, buf1, b2, row_start, csr_src, buf2);
    // MLP factorization: A = h2@Wm1[:, :64].T (buf0), B = h2@Wm1[:, 64:128].T (buf1)
    dual_gemm_kernel<64><<<(NN + 31) / 32, 256, 0, stream>>>(buf2, Wm1, 129, Wm1 + 64, 129, buf0, buf1);
    // Per-query head
    query_kernel<<<(NQ + 3) / 4, 256, 0, stream>>>(uv, tf, buf0, buf1, Wm1, bm1, Wm2, bm2, out);
}

// Round 3
// 296.168 us; speedup vs baseline: 2.9711x; 1.5552x over previous
//
#include <hip/hip_runtime.h>

// EtaGNN: 2x SAGE-conv (mean agg) + factorized MLP link predictor.
// Strategy: project-then-aggregate (linearity of mean), CSR gather (no f32 atomics),
// factorized query head (A[u]+B[v]+t*wt).
// R1: register-light dual_gemm (R0 spilled at 256 VGPR -> 360MB scratch traffic/dispatch).
// R2: latency-hiding everywhere. GEMM: X tile in LDS (broadcast reads), one xv live.
//     agg: 16-lane groups + float4 + 4-deep gather MLP. query: grid-stride, 16-lane
//     groups + float4, hoisted constants, unroll 2.

constexpr int NN = 50000;   // nodes
constexpr int NE = 800000;  // edges
constexpr int NQ = 400000;  // queries

// ---------------- CSR build ----------------
__global__ void count_kernel(const int* __restrict__ dst, int* __restrict__ cnt) {
    int e = blockIdx.x * 256 + threadIdx.x;
    if (e < NE) atomicAdd(&cnt[dst[e]], 1);
}

constexpr int SCHUNK = 1024;
constexpr int SBLK = (NN + SCHUNK - 1) / SCHUNK;  // 49 blocks

__global__ void scan_sum_kernel(const int* __restrict__ cnt, int* __restrict__ bsum) {
    __shared__ int sd[256];
    int t = threadIdx.x;
    int base = blockIdx.x * SCHUNK;
    int s = 0;
#pragma unroll
    for (int j = 0; j < 4; ++j) {
        int i = base + t + j * 256;
        if (i < NN) s += cnt[i];
    }
    sd[t] = s; __syncthreads();
    for (int off = 128; off > 0; off >>= 1) {
        if (t < off) sd[t] += sd[t + off];
        __syncthreads();
    }
    if (t == 0) bsum[blockIdx.x] = sd[0];
}

__global__ void scan_block_kernel(int* bsum) {  // 1 wave, exclusive scan in place
    int t = threadIdx.x;
    int orig = (t < SBLK) ? bsum[t] : 0;
    int v = orig;
#pragma unroll
    for (int off = 1; off < 64; off <<= 1) {
        int w = __shfl_up(v, off);
        if (t >= off) v += w;
    }
    if (t < SBLK) bsum[t] = v - orig;
}

__global__ void scan_write_kernel(const int* __restrict__ bsum, int* __restrict__ row_start,
                                  int* __restrict__ cursor /* in: counts, out: cursor */) {
    __shared__ int wsum[4];
    int t = threadIdx.x, lane = t & 63, wid = t >> 6;
    int base = blockIdx.x * SCHUNK;
    int v[4]; int s = 0;
#pragma unroll
    for (int j = 0; j < 4; ++j) {
        int i = base + t * 4 + j;
        v[j] = (i < NN) ? cursor[i] : 0;
        s += v[j];
    }
    int orig = s;
#pragma unroll
    for (int off = 1; off < 64; off <<= 1) {
        int w = __shfl_up(s, off);
        if (lane >= off) s += w;
    }
    if (lane == 63) wsum[wid] = s;
    __syncthreads();
    int woff = 0;
    for (int w = 0; w < wid; ++w) woff += wsum[w];
    int excl = bsum[blockIdx.x] + woff + (s - orig);
#pragma unroll
    for (int j = 0; j < 4; ++j) {
        int i = base + t * 4 + j;
        if (i <= NN) {
            row_start[i] = excl;
            if (i < NN) { cursor[i] = excl; excl += v[j]; }
        }
    }
}

__global__ void fill_kernel(const int* __restrict__ src, const int* __restrict__ dst,
                            int* __restrict__ cursor, int* __restrict__ csr_src) {
    int e = blockIdx.x * 256 + threadIdx.x;
    if (e < NE) {
        int p = atomicAdd(&cursor[dst[e]], 1);
        csr_src[p] = src[e];
    }
}

// ---------------- dual GEMM: outA = in @ Wa.T, outB = in @ Wb.T  (Cout=64) ----------------
// 256 threads = 4 waves; wave owns 8 rows, lane owns 1 col of each output.
// X tile in LDS (broadcast reads, low latency); W tiles [k][c] padded.
template <int K>
__global__ __launch_bounds__(256, 3) void dual_gemm_kernel(
    const float* __restrict__ in,
    const float* __restrict__ Wa, int wsA,
    const float* __restrict__ Wb, int wsB,
    float* __restrict__ outA, float* __restrict__ outB) {
    __shared__ float WaT[64][65];  // [k][c]
    __shared__ float WbT[64][65];
    __shared__ float X[32][K];
    int t = threadIdx.x;
    int c = t & 63, g = t >> 6;
    int rbase = blockIdx.x * 32;
    // stage X: coalesced float4 loads, linear LDS writes
    {
        constexpr int KV = K / 4;
        const float4* in4 = (const float4*)in;
        float4* X4 = (float4*)&X[0][0];
        for (int idx = t; idx < 32 * KV; idx += 256) {
            int r = idx / KV, kv = idx - r * KV;
            int gr = rbase + r; if (gr >= NN) gr = NN - 1;  // clamp (stores guarded)
            X4[idx] = in4[(size_t)gr * KV + kv];
        }
    }
    float accA[8] = {0.f, 0.f, 0.f, 0.f, 0.f, 0.f, 0.f, 0.f};
    float accB[8] = {0.f, 0.f, 0.f, 0.f, 0.f, 0.f, 0.f, 0.f};
    for (int ph = 0; ph < K / 64; ++ph) {
        __syncthreads();  // X ready / previous phase's W consumed
        for (int idx = t; idx < 4096; idx += 256) {
            int cc = idx >> 6, kk = idx & 63;
            WaT[kk][cc] = Wa[cc * wsA + ph * 64 + kk];
            WbT[kk][cc] = Wb[cc * wsB + ph * 64 + kk];
        }
        __syncthreads();
        for (int k2 = 0; k2 < 64; k2 += 4) {
            float wa0 = WaT[k2 + 0][c], wa1 = WaT[k2 + 1][c];
            float wa2 = WaT[k2 + 2][c], wa3 = WaT[k2 + 3][c];
            float wb0 = WbT[k2 + 0][c], wb1 = WbT[k2 + 1][c];
            float wb2 = WbT[k2 + 2][c], wb3 = WbT[k2 + 3][c];
#pragma unroll
            for (int j = 0; j < 8; ++j) {
                float4 xv = *reinterpret_cast<const float4*>(&X[g * 8 + j][ph * 64 + k2]);
                accA[j] = fmaf(xv.x, wa0, accA[j]);
                accB[j] = fmaf(xv.x, wb0, accB[j]);
                accA[j] = fmaf(xv.y, wa1, accA[j]);
                accB[j] = fmaf(xv.y, wb1, accB[j]);
                accA[j] = fmaf(xv.z, wa2, accA[j]);
                accB[j] = fmaf(xv.z, wb2, accB[j]);
                accA[j] = fmaf(xv.w, wa3, accA[j]);
                accB[j] = fmaf(xv.w, wb3, accB[j]);
            }
        }
    }
#pragma unroll
    for (int j = 0; j < 8; ++j) {
        int gr = rbase + g * 8 + j;
        if (gr < NN) {
            outA[(size_t)gr * 64 + c] = accA[j];
            outB[(size_t)gr * 64 + c] = accB[j];
        }
    }
}

// ---------------- aggregation: out = relu(sum(p[src])/max(deg,1) + bias + selfp) ----------------
// 16 lanes per node (float4/lane), 4 nodes per wave, 4-deep gather MLP.
__global__ __launch_bounds__(256) void agg_kernel(
    const float* __restrict__ p, const float* __restrict__ selfp,
    const float* __restrict__ bias, const int* __restrict__ row_start,
    const int* __restrict__ csr_src, float* __restrict__ out) {
    int node = blockIdx.x * 16 + (threadIdx.x >> 4);
    int sub = threadIdx.x & 15;
    if (node >= NN) return;
    const float4* p4 = (const float4*)p;
    int s0 = row_start[node], s1 = row_start[node + 1];
    float4 acc = make_float4(0.f, 0.f, 0.f, 0.f);
    int e = s0;
    for (; e + 4 <= s1; e += 4) {
        int i0 = csr_src[e + 0], i1 = csr_src[e + 1];
        int i2 = csr_src[e + 2], i3 = csr_src[e + 3];
        float4 a = p4[(size_t)i0 * 16 + sub];
        float4 b = p4[(size_t)i1 * 16 + sub];
        float4 cc = p4[(size_t)i2 * 16 + sub];
        float4 d = p4[(size_t)i3 * 16 + sub];
        acc.x += (a.x + b.x) + (cc.x + d.x);
        acc.y += (a.y + b.y) + (cc.y + d.y);
        acc.z += (a.z + b.z) + (cc.z + d.z);
        acc.w += (a.w + b.w) + (cc.w + d.w);
    }
    for (; e < s1; ++e) {
        int s = csr_src[e];
        float4 a = p4[(size_t)s * 16 + sub];
        acc.x += a.x; acc.y += a.y; acc.z += a.z; acc.w += a.w;
    }
    float inv = 1.f / fmaxf((float)(s1 - s0), 1.f);
    float4 self = ((const float4*)selfp)[(size_t)node * 16 + sub];
    float4 bs = ((const float4*)bias)[sub];
    float4 r;
    r.x = fmaxf(fmaf(acc.x, inv, bs.x + self.x), 0.f);
    r.y = fmaxf(fmaf(acc.y, inv, bs.y + self.y), 0.f);
    r.z = fmaxf(fmaf(acc.z, inv, bs.z + self.z), 0.f);
    r.w = fmaxf(fmaf(acc.w, inv, bs.w + self.w), 0.f);
    ((float4*)out)[(size_t)node * 16 + sub] = r;
}

// ---------------- query head: out = relu(A[u]+B[v]+t*wt+bm1) . Wm2 + bm2 ----------------
// grid-stride; 16 lanes per query (float4/lane), constants hoisted.
__global__ __launch_bounds__(256) void query_kernel(
    const int* __restrict__ uv, const float* __restrict__ tf,
    const float* __restrict__ A, const float* __restrict__ B,
    const float* __restrict__ Wm1, const float* __restrict__ bm1,
    const float* __restrict__ Wm2, const float* __restrict__ bm2,
    float* __restrict__ out) {
    int sub = threadIdx.x & 15;
    int gidx = (blockIdx.x * 256 + threadIdx.x) >> 4;
    int ngroups = (gridDim.x * 256) >> 4;
    const float4* A4 = (const float4*)A;
    const float4* B4 = (const float4*)B;
    const int2* uv2 = (const int2*)uv;
    // hoisted per-lane constants (features sub*4 .. sub*4+3)
    float4 wt4, bm14, wm24;
    {
        int f = sub * 4;
        wt4 = make_float4(Wm1[(f + 0) * 129 + 128], Wm1[(f + 1) * 129 + 128],
                          Wm1[(f + 2) * 129 + 128], Wm1[(f + 3) * 129 + 128]);
        bm14 = ((const float4*)bm1)[sub];
        wm24 = ((const float4*)Wm2)[sub];
    }
    float bm2s = bm2[0];
#pragma unroll 2
    for (int q = gidx; q < NQ; q += ngroups) {
        int2 uvq = uv2[q];
        float t = tf[q];
        float4 a = A4[(size_t)uvq.x * 16 + sub];
        float4 b = B4[(size_t)uvq.y * 16 + sub];
        float zx = fmaxf(a.x + b.x + t * wt4.x + bm14.x, 0.f) * wm24.x;
        float zy = fmaxf(a.y + b.y + t * wt4.y + bm14.y, 0.f) * wm24.y;
        float zz = fmaxf(a.z + b.z + t * wt4.z + bm14.z, 0.f) * wm24.z;
        float zw = fmaxf(a.w + b.w + t * wt4.w + bm14.w, 0.f) * wm24.w;
        float s = (zx + zy) + (zz + zw);
        s += __shfl_down(s, 8, 16);
        s += __shfl_down(s, 4, 16);
        s += __shfl_down(s, 2, 16);
        s += __shfl_down(s, 1, 16);
        if (sub == 0) out[q] = s + bm2s;
    }
}

extern "C" void kernel_launch(void* const* d_in, const int* in_sizes, int n_in,
                              void* d_out, int out_size, void* d_ws, size_t ws_size,
                              hipStream_t stream) {
    const float* x   = (const float*)d_in[0];
    const int*   ei  = (const int*)d_in[1];
    const int*   uv  = (const int*)d_in[2];
    const float* tf  = (const float*)d_in[3];
    const float* W1l = (const float*)d_in[4];
    const float* b1  = (const float*)d_in[5];
    const float* W1r = (const float*)d_in[6];
    const float* W2l = (const float*)d_in[7];
    const float* b2  = (const float*)d_in[8];
    const float* W2r = (const float*)d_in[9];
    const float* Wm1 = (const float*)d_in[10];
    const float* bm1 = (const float*)d_in[11];
    const float* Wm2 = (const float*)d_in[12];
    const float* bm2 = (const float*)d_in[13];
    float* out = (float*)d_out;

    char* ws = (char*)d_ws;
    size_t off = 0;
    auto take = [&](size_t bytes) -> void* {
        void* p = ws + off;
        off = (off + bytes + 255) & ~(size_t)255;
        return p;
    };
    int* row_start = (int*)take((NN + 1) * sizeof(int));
    int* cursor    = (int*)take((size_t)NN * sizeof(int));
    int* csr_src   = (int*)take((size_t)NE * sizeof(int));
    int* bsum      = (int*)take(64 * sizeof(int));
    float* buf0 = (float*)take((size_t)NN * 64 * sizeof(float));
    float* buf1 = (float*)take((size_t)NN * 64 * sizeof(float));
    float* buf2 = (float*)take((size_t)NN * 64 * sizeof(float));
    (void)in_sizes; (void)n_in; (void)out_size; (void)ws_size;

    const int* esrc = ei;
    const int* edst = ei + NE;

    // CSR build (counts -> exclusive scan -> fill)
    hipMemsetAsync(cursor, 0, NN * sizeof(int), stream);
    count_kernel<<<(NE + 255) / 256, 256, 0, stream>>>(edst, cursor);
    scan_sum_kernel<<<SBLK, 256, 0, stream>>>(cursor, bsum);
    scan_block_kernel<<<1, 64, 0, stream>>>(bsum);
    scan_write_kernel<<<SBLK, 256, 0, stream>>>(bsum, row_start, cursor);
    fill_kernel<<<(NE + 255) / 256, 256, 0, stream>>>(esrc, edst, cursor, csr_src);

    // Layer 1: p1 = x@W1l.T (buf0), xr = x@W1r.T (buf1); h1 = relu(mean+b1+xr) (buf2)
    dual_gemm_kernel<128><<<(NN + 31) / 32, 256, 0, stream>>>(x, W1l, 128, W1r, 128, buf0, buf1);
    agg_kernel<<<(NN + 15) / 16, 256, 0, stream>>>(buf0, buf1, b1, row_start, csr_src, buf2);
    // Layer 2
    dual_gemm_kernel<64><<<(NN + 31) / 32, 256, 0, stream>>>(buf2, W2l, 64, W2r, 64, buf0, buf1);
    agg_kernel<<<(NN + 15) / 16, 256, 0, stream>>>(buf0, buf1, b2, row_start, csr_src, buf2);
    // MLP factorization: A = h2@Wm1[:, :64].T (buf0), B = h2@Wm1[:, 64:128].T (buf1)
    dual_gemm_kernel<64><<<(NN + 31) / 32, 256, 0, stream>>>(buf2, Wm1, 129, Wm1 + 64, 129, buf0, buf1);
    // Per-query head
    query_kernel<<<2048, 256, 0, stream>>>(uv, tf, buf0, buf1, Wm1, bm1, Wm2, bm2, out);
}

// Round 4
// 292.455 us; speedup vs baseline: 3.0088x; 1.0127x over previous
//
#include <hip/hip_runtime.h>

// EtaGNN: 2x SAGE-conv (mean agg) + factorized MLP link predictor.
// Strategy: project-then-aggregate (linearity of mean), CSR gather (no f32 atomics),
// factorized query head (A[u]+B[v]+t*wt).
// R1: register-light dual_gemm (R0 spilled at 256 VGPR).
// R2: X tile in LDS, agg/query 16-lane float4 groups.
// R3: GEMM v4 - W via prefetched global float4 (no W LDS, no per-phase barriers),
//     64 rows/block 16 rows/wave -> VALU-bound; Wm1 pre-split to aligned buffers.

constexpr int NN = 50000;   // nodes
constexpr int NE = 800000;  // edges
constexpr int NQ = 400000;  // queries

// ---------------- CSR build ----------------
__global__ void count_kernel(const int* __restrict__ dst, int* __restrict__ cnt) {
    int e = blockIdx.x * 256 + threadIdx.x;
    if (e < NE) atomicAdd(&cnt[dst[e]], 1);
}

constexpr int SCHUNK = 1024;
constexpr int SBLK = (NN + SCHUNK - 1) / SCHUNK;  // 49 blocks

__global__ void scan_sum_kernel(const int* __restrict__ cnt, int* __restrict__ bsum) {
    __shared__ int sd[256];
    int t = threadIdx.x;
    int base = blockIdx.x * SCHUNK;
    int s = 0;
#pragma unroll
    for (int j = 0; j < 4; ++j) {
        int i = base + t + j * 256;
        if (i < NN) s += cnt[i];
    }
    sd[t] = s; __syncthreads();
    for (int off = 128; off > 0; off >>= 1) {
        if (t < off) sd[t] += sd[t + off];
        __syncthreads();
    }
    if (t == 0) bsum[blockIdx.x] = sd[0];
}

__global__ void scan_block_kernel(int* bsum) {  // 1 wave, exclusive scan in place
    int t = threadIdx.x;
    int orig = (t < SBLK) ? bsum[t] : 0;
    int v = orig;
#pragma unroll
    for (int off = 1; off < 64; off <<= 1) {
        int w = __shfl_up(v, off);
        if (t >= off) v += w;
    }
    if (t < SBLK) bsum[t] = v - orig;
}

__global__ void scan_write_kernel(const int* __restrict__ bsum, int* __restrict__ row_start,
                                  int* __restrict__ cursor /* in: counts, out: cursor */) {
    __shared__ int wsum[4];
    int t = threadIdx.x, lane = t & 63, wid = t >> 6;
    int base = blockIdx.x * SCHUNK;
    int v[4]; int s = 0;
#pragma unroll
    for (int j = 0; j < 4; ++j) {
        int i = base + t * 4 + j;
        v[j] = (i < NN) ? cursor[i] : 0;
        s += v[j];
    }
    int orig = s;
#pragma unroll
    for (int off = 1; off < 64; off <<= 1) {
        int w = __shfl_up(s, off);
        if (lane >= off) s += w;
    }
    if (lane == 63) wsum[wid] = s;
    __syncthreads();
    int woff = 0;
    for (int w = 0; w < wid; ++w) woff += wsum[w];
    int excl = bsum[blockIdx.x] + woff + (s - orig);
#pragma unroll
    for (int j = 0; j < 4; ++j) {
        int i = base + t * 4 + j;
        if (i <= NN) {
            row_start[i] = excl;
            if (i < NN) { cursor[i] = excl; excl += v[j]; }
        }
    }
}

__global__ void fill_kernel(const int* __restrict__ src, const int* __restrict__ dst,
                            int* __restrict__ cursor, int* __restrict__ csr_src) {
    int e = blockIdx.x * 256 + threadIdx.x;
    if (e < NE) {
        int p = atomicAdd(&cursor[dst[e]], 1);
        csr_src[p] = src[e];
    }
}

// ---------------- Wm1 split: WmA[64][64], WmB[64][64], wt[64] ----------------
__global__ void prep_wm1_kernel(const float* __restrict__ Wm1, float* __restrict__ WmA,
                                float* __restrict__ WmB, float* __restrict__ wt) {
    int t = blockIdx.x * 256 + threadIdx.x;
    if (t < 64 * 64) {
        int c = t >> 6, k = t & 63;
        WmA[t] = Wm1[c * 129 + k];
        WmB[t] = Wm1[c * 129 + 64 + k];
    }
    if (t < 64) wt[t] = Wm1[t * 129 + 128];
}

// ---------------- dual GEMM: outA = in @ Wa.T, outB = in @ Wb.T  (Cout=64, row stride K) ----
// 256 threads = 4 waves; wave owns 16 rows, lane owns 1 col of each output.
// X tile in LDS (uniform broadcast b128 reads); W streamed from global per-thread
// (own row, L1/L2-resident) with 1-step register prefetch. One barrier total.
template <int K>
__global__ __launch_bounds__(256, 4) void dual_gemm_kernel(
    const float* __restrict__ in,
    const float* __restrict__ Wa, const float* __restrict__ Wb,
    float* __restrict__ outA, float* __restrict__ outB) {
    __shared__ float X[64][K];
    int t = threadIdx.x;
    int c = t & 63, g = t >> 6;
    int rbase = blockIdx.x * 64;
    constexpr int KV = K / 4;
    {
        const float4* in4 = (const float4*)in;
        float4* X4 = (float4*)&X[0][0];
        for (int idx = t; idx < 64 * KV; idx += 256) {
            int r = idx / KV, kv = idx - r * KV;
            int gr = rbase + r; if (gr >= NN) gr = NN - 1;  // clamp; stores guarded
            X4[idx] = in4[(size_t)gr * KV + kv];
        }
    }
    float accA[16], accB[16];
#pragma unroll
    for (int j = 0; j < 16; ++j) { accA[j] = 0.f; accB[j] = 0.f; }
    const float* wap = Wa + (size_t)c * K;
    const float* wbp = Wb + (size_t)c * K;
    float4 wa = *(const float4*)wap;
    float4 wb = *(const float4*)wbp;
    __syncthreads();
#pragma unroll 2
    for (int k2 = 0; k2 < K; k2 += 4) {
        float4 wan = wa, wbn = wb;
        if (k2 + 4 < K) {
            wan = *(const float4*)(wap + k2 + 4);
            wbn = *(const float4*)(wbp + k2 + 4);
        }
#pragma unroll
        for (int j = 0; j < 16; ++j) {
            float4 xv = *reinterpret_cast<const float4*>(&X[g * 16 + j][k2]);
            accA[j] = fmaf(xv.x, wa.x, accA[j]);
            accB[j] = fmaf(xv.x, wb.x, accB[j]);
            accA[j] = fmaf(xv.y, wa.y, accA[j]);
            accB[j] = fmaf(xv.y, wb.y, accB[j]);
            accA[j] = fmaf(xv.z, wa.z, accA[j]);
            accB[j] = fmaf(xv.z, wb.z, accB[j]);
            accA[j] = fmaf(xv.w, wa.w, accA[j]);
            accB[j] = fmaf(xv.w, wb.w, accB[j]);
        }
        wa = wan; wb = wbn;
    }
#pragma unroll
    for (int j = 0; j < 16; ++j) {
        int gr = rbase + g * 16 + j;
        if (gr < NN) {
            outA[(size_t)gr * 64 + c] = accA[j];
            outB[(size_t)gr * 64 + c] = accB[j];
        }
    }
}

// ---------------- aggregation: out = relu(sum(p[src])/max(deg,1) + bias + selfp) ----------------
// 16 lanes per node (float4/lane), 4 nodes per wave, 4-deep gather MLP.
__global__ __launch_bounds__(256) void agg_kernel(
    const float* __restrict__ p, const float* __restrict__ selfp,
    const float* __restrict__ bias, const int* __restrict__ row_start,
    const int* __restrict__ csr_src, float* __restrict__ out) {
    int node = blockIdx.x * 16 + (threadIdx.x >> 4);
    int sub = threadIdx.x & 15;
    if (node >= NN) return;
    const float4* p4 = (const float4*)p;
    int s0 = row_start[node], s1 = row_start[node + 1];
    float4 acc = make_float4(0.f, 0.f, 0.f, 0.f);
    int e = s0;
    for (; e + 4 <= s1; e += 4) {
        int i0 = csr_src[e + 0], i1 = csr_src[e + 1];
        int i2 = csr_src[e + 2], i3 = csr_src[e + 3];
        float4 a = p4[(size_t)i0 * 16 + sub];
        float4 b = p4[(size_t)i1 * 16 + sub];
        float4 cc = p4[(size_t)i2 * 16 + sub];
        float4 d = p4[(size_t)i3 * 16 + sub];
        acc.x += (a.x + b.x) + (cc.x + d.x);
        acc.y += (a.y + b.y) + (cc.y + d.y);
        acc.z += (a.z + b.z) + (cc.z + d.z);
        acc.w += (a.w + b.w) + (cc.w + d.w);
    }
    for (; e < s1; ++e) {
        int s = csr_src[e];
        float4 a = p4[(size_t)s * 16 + sub];
        acc.x += a.x; acc.y += a.y; acc.z += a.z; acc.w += a.w;
    }
    float inv = 1.f / fmaxf((float)(s1 - s0), 1.f);
    float4 self = ((const float4*)selfp)[(size_t)node * 16 + sub];
    float4 bs = ((const float4*)bias)[sub];
    float4 r;
    r.x = fmaxf(fmaf(acc.x, inv, bs.x + self.x), 0.f);
    r.y = fmaxf(fmaf(acc.y, inv, bs.y + self.y), 0.f);
    r.z = fmaxf(fmaf(acc.z, inv, bs.z + self.z), 0.f);
    r.w = fmaxf(fmaf(acc.w, inv, bs.w + self.w), 0.f);
    ((float4*)out)[(size_t)node * 16 + sub] = r;
}

// ---------------- query head: out = relu(A[u]+B[v]+t*wt+bm1) . Wm2 + bm2 ----------------
// grid-stride; 16 lanes per query (float4/lane), constants hoisted.
__global__ __launch_bounds__(256) void query_kernel(
    const int* __restrict__ uv, const float* __restrict__ tf,
    const float* __restrict__ A, const float* __restrict__ B,
    const float* __restrict__ wt, const float* __restrict__ bm1,
    const float* __restrict__ Wm2, const float* __restrict__ bm2,
    float* __restrict__ out) {
    int sub = threadIdx.x & 15;
    int gidx = (blockIdx.x * 256 + threadIdx.x) >> 4;
    int ngroups = (gridDim.x * 256) >> 4;
    const float4* A4 = (const float4*)A;
    const float4* B4 = (const float4*)B;
    const int2* uv2 = (const int2*)uv;
    float4 wt4 = ((const float4*)wt)[sub];
    float4 bm14 = ((const float4*)bm1)[sub];
    float4 wm24 = ((const float4*)Wm2)[sub];
    float bm2s = bm2[0];
#pragma unroll 2
    for (int q = gidx; q < NQ; q += ngroups) {
        int2 uvq = uv2[q];
        float t = tf[q];
        float4 a = A4[(size_t)uvq.x * 16 + sub];
        float4 b = B4[(size_t)uvq.y * 16 + sub];
        float zx = fmaxf(a.x + b.x + t * wt4.x + bm14.x, 0.f) * wm24.x;
        float zy = fmaxf(a.y + b.y + t * wt4.y + bm14.y, 0.f) * wm24.y;
        float zz = fmaxf(a.z + b.z + t * wt4.z + bm14.z, 0.f) * wm24.z;
        float zw = fmaxf(a.w + b.w + t * wt4.w + bm14.w, 0.f) * wm24.w;
        float s = (zx + zy) + (zz + zw);
        s += __shfl_down(s, 8, 16);
        s += __shfl_down(s, 4, 16);
        s += __shfl_down(s, 2, 16);
        s += __shfl_down(s, 1, 16);
        if (sub == 0) out[q] = s + bm2s;
    }
}

extern "C" void kernel_launch(void* const* d_in, const int* in_sizes, int n_in,
                              void* d_out, int out_size, void* d_ws, size_t ws_size,
                              hipStream_t stream) {
    const float* x   = (const float*)d_in[0];
    const int*   ei  = (const int*)d_in[1];
    const int*   uv  = (const int*)d_in[2];
    const float* tf  = (const float*)d_in[3];
    const float* W1l = (const float*)d_in[4];
    const float* b1  = (const float*)d_in[5];
    const float* W1r = (const float*)d_in[6];
    const float* W2l = (const float*)d_in[7];
    const float* b2  = (const float*)d_in[8];
    const float* W2r = (const float*)d_in[9];
    const float* Wm1 = (const float*)d_in[10];
    const float* bm1 = (const float*)d_in[11];
    const float* Wm2 = (const float*)d_in[12];
    const float* bm2 = (const float*)d_in[13];
    float* out = (float*)d_out;

    char* ws = (char*)d_ws;
    size_t off = 0;
    auto take = [&](size_t bytes) -> void* {
        void* p = ws + off;
        off = (off + bytes + 255) & ~(size_t)255;
        return p;
    };
    int* row_start = (int*)take((NN + 1) * sizeof(int));
    int* cursor    = (int*)take((size_t)NN * sizeof(int));
    int* csr_src   = (int*)take((size_t)NE * sizeof(int));
    int* bsum      = (int*)take(64 * sizeof(int));
    float* WmA = (float*)take(64 * 64 * sizeof(float));
    float* WmB = (float*)take(64 * 64 * sizeof(float));
    float* wt  = (float*)take(64 * sizeof(float));
    float* buf0 = (float*)take((size_t)NN * 64 * sizeof(float));
    float* buf1 = (float*)take((size_t)NN * 64 * sizeof(float));
    float* buf2 = (float*)take((size_t)NN * 64 * sizeof(float));
    (void)in_sizes; (void)n_in; (void)out_size; (void)ws_size;

    const int* esrc = ei;
    const int* edst = ei + NE;

    // CSR build (counts -> exclusive scan -> fill) + Wm1 split
    hipMemsetAsync(cursor, 0, NN * sizeof(int), stream);
    count_kernel<<<(NE + 255) / 256, 256, 0, stream>>>(edst, cursor);
    scan_sum_kernel<<<SBLK, 256, 0, stream>>>(cursor, bsum);
    scan_block_kernel<<<1, 64, 0, stream>>>(bsum);
    scan_write_kernel<<<SBLK, 256, 0, stream>>>(bsum, row_start, cursor);
    fill_kernel<<<(NE + 255) / 256, 256, 0, stream>>>(esrc, edst, cursor, csr_src);
    prep_wm1_kernel<<<16, 256, 0, stream>>>(Wm1, WmA, WmB, wt);

    // Layer 1: p1 = x@W1l.T (buf0), xr = x@W1r.T (buf1); h1 = relu(mean+b1+xr) (buf2)
    dual_gemm_kernel<128><<<(NN + 63) / 64, 256, 0, stream>>>(x, W1l, W1r, buf0, buf1);
    agg_kernel<<<(NN + 15) / 16, 256, 0, stream>>>(buf0, buf1, b1, row_start, csr_src, buf2);
    // Layer 2
    dual_gemm_kernel<64><<<(NN + 63) / 64, 256, 0, stream>>>(buf2, W2l, W2r, buf0, buf1);
    agg_kernel<<<(NN + 15) / 16, 256, 0, stream>>>(buf0, buf1, b2, row_start, csr_src, buf2);
    // MLP factorization: A = h2@WmA.T (buf0), B = h2@WmB.T (buf1)
    dual_gemm_kernel<64><<<(NN + 63) / 64, 256, 0, stream>>>(buf2, WmA, WmB, buf0, buf1);
    // Per-query head
    query_kernel<<<2048, 256, 0, stream>>>(uv, tf, buf0, buf1, wt, bm1, Wm2, bm2, out);
}